// Round 1
// baseline (517.347 us; speedup 1.0000x reference)
//
#include <hip/hip_runtime.h>
#include <hip/hip_bf16.h>
#include <math.h>

// Problem constants
#define Bb 2
#define Hh 128
#define Wd 128
#define Cc 96
#define Dd 192
#define Ll 16384        // Hh*Wd
#define Nn 16
#define Rr 6
#define DL 3145728      // Dd*Ll
#define NCHUNK 128
#define CLEN 128

__device__ __forceinline__ float siluf(float v) { return v / (1.f + __expf(-v)); }
__device__ __forceinline__ float geluf(float v) { return 0.5f * v * (1.f + erff(v * 0.70710678118654752f)); }
__device__ __forceinline__ float softplusf(float v) {
    float a = fabsf(v);
    return fmaxf(v, 0.f) + log1pf(__expf(-a));
}

// ---------------------------------------------------------------------------
// K2: GEMM with K=96.  A (M x 96) pos-major, W (Nout x 96) row-major.
// MODE 0: A = x, LN fused (ln over 96 channels); outputs o<192 -> xi (B,D,L),
//         o>=192 -> z (pos-major (B*L,192)).
// MODE 1: A = high_branch_low (no LN); all outputs -> (B,D,L).
// ---------------------------------------------------------------------------
template <int MODE>
__global__ __launch_bounds__(256) void gemm96_k(
    const float* __restrict__ A, const float* __restrict__ W,
    float* __restrict__ outA, float* __restrict__ outB,
    const float* __restrict__ lng, const float* __restrict__ lnb)
{
    __shared__ float sA[96 * 68];   // [k][row], padded row stride 68
    __shared__ float sW[96 * 68];
    __shared__ float redS[512];
    __shared__ float meanS[64], rstdS[64];

    const int t = threadIdx.x;
    const int m0 = blockIdx.x * 64;
    const int n0 = blockIdx.y * 64;

    #pragma unroll
    for (int i = 0; i < 6; ++i) {
        int idx = t + i * 256;          // float4 index, 0..1535
        int row = idx / 24, c4 = idx % 24;
        float4 v = *reinterpret_cast<const float4*>(A + (size_t)(m0 + row) * 96 + c4 * 4);
        int c = c4 * 4;
        sA[(c + 0) * 68 + row] = v.x; sA[(c + 1) * 68 + row] = v.y;
        sA[(c + 2) * 68 + row] = v.z; sA[(c + 3) * 68 + row] = v.w;
    }
    #pragma unroll
    for (int i = 0; i < 6; ++i) {
        int idx = t + i * 256;
        int row = idx / 24, c4 = idx % 24;
        float4 v = *reinterpret_cast<const float4*>(W + (size_t)(n0 + row) * 96 + c4 * 4);
        int c = c4 * 4;
        sW[(c + 0) * 68 + row] = v.x; sW[(c + 1) * 68 + row] = v.y;
        sW[(c + 2) * 68 + row] = v.z; sW[(c + 3) * 68 + row] = v.w;
    }
    __syncthreads();

    if (MODE == 0) {
        // fused LayerNorm over the 96 channels of each of the 64 rows
        int r = t & 63, part = t >> 6;          // 4 parts x 24 channels
        float s = 0.f, s2 = 0.f;
        for (int k = part * 24; k < part * 24 + 24; ++k) {
            float v = sA[k * 68 + r]; s += v; s2 += v * v;
        }
        redS[part * 64 + r] = s; redS[256 + part * 64 + r] = s2;
        __syncthreads();
        if (t < 64) {
            float ts = 0.f, ts2 = 0.f;
            #pragma unroll
            for (int p = 0; p < 4; ++p) { ts += redS[p * 64 + t]; ts2 += redS[256 + p * 64 + t]; }
            float mean = ts * (1.f / 96.f);
            float var = ts2 * (1.f / 96.f) - mean * mean;
            meanS[t] = mean; rstdS[t] = rsqrtf(var + 1e-5f);
        }
        __syncthreads();
        for (int k = part * 24; k < part * 24 + 24; ++k) {
            float v = sA[k * 68 + r];
            sA[k * 68 + r] = (v - meanS[r]) * rstdS[r] * lng[k] + lnb[k];
        }
        __syncthreads();
    }

    const int tc = t & 15, tr = t >> 4;
    float acc[4][4];
    #pragma unroll
    for (int q = 0; q < 4; ++q)
        #pragma unroll
        for (int j = 0; j < 4; ++j) acc[q][j] = 0.f;

    #pragma unroll 4
    for (int k = 0; k < 96; ++k) {
        float4 a4 = *reinterpret_cast<const float4*>(&sA[k * 68 + tr * 4]);
        float4 w4 = *reinterpret_cast<const float4*>(&sW[k * 68 + tc * 4]);
        acc[0][0] += a4.x * w4.x; acc[0][1] += a4.x * w4.y; acc[0][2] += a4.x * w4.z; acc[0][3] += a4.x * w4.w;
        acc[1][0] += a4.y * w4.x; acc[1][1] += a4.y * w4.y; acc[1][2] += a4.y * w4.z; acc[1][3] += a4.y * w4.w;
        acc[2][0] += a4.z * w4.x; acc[2][1] += a4.z * w4.y; acc[2][2] += a4.z * w4.z; acc[2][3] += a4.z * w4.w;
        acc[3][0] += a4.w * w4.x; acc[3][1] += a4.w * w4.y; acc[3][2] += a4.w * w4.z; acc[3][3] += a4.w * w4.w;
    }

    #pragma unroll
    for (int q = 0; q < 4; ++q) {
        int m = m0 + tr * 4 + q;
        int b = m >> 14, l = m & 16383;
        #pragma unroll
        for (int j = 0; j < 4; ++j) {
            int o = n0 + tc * 4 + j;
            float v = acc[q][j];
            if (MODE == 0) {
                if (o < Dd) outA[(size_t)b * DL + (size_t)o * Ll + l] = v;
                else        outB[(size_t)m * Dd + (o - Dd)] = v;
            } else {
                outA[(size_t)b * DL + (size_t)o * Ll + l] = v;
            }
        }
    }
}

// ---------------------------------------------------------------------------
// K3: depthwise 3x3 conv, pad 1, + bias + SiLU.  (B,D,H,W) channel-major.
// ---------------------------------------------------------------------------
__global__ __launch_bounds__(128) void conv3x3_k(
    const float* __restrict__ xin, const float* __restrict__ cw,
    const float* __restrict__ cb, float* __restrict__ xout)
{
    int w = threadIdx.x;      // 0..127
    int h = blockIdx.x;       // 0..127
    int d = blockIdx.y;       // 0..191
    int b = blockIdx.z;
    const float* base = xin + (size_t)(b * Dd + d) * Ll;
    float wgt[9];
    #pragma unroll
    for (int i = 0; i < 9; ++i) wgt[i] = cw[d * 9 + i];
    float acc = cb[d];
    #pragma unroll
    for (int ky = 0; ky < 3; ++ky) {
        int hh = h + ky - 1;
        if (hh < 0 || hh >= Hh) continue;
        #pragma unroll
        for (int kx = 0; kx < 3; ++kx) {
            int ww = w + kx - 1;
            if (ww < 0 || ww >= Wd) continue;
            acc += wgt[ky * 3 + kx] * base[hh * Wd + ww];
        }
    }
    xout[(size_t)(b * Dd + d) * Ll + h * Wd + w] = siluf(acc);
}

// ---------------------------------------------------------------------------
// K4a: low_dbl rows 6..37 + SimpleGate for B and C.  One thread per position.
// ---------------------------------------------------------------------------
__global__ __launch_bounds__(256) void lowdbl_gates_k(
    const float* __restrict__ low, const float* __restrict__ wl,
    const float* __restrict__ b1, const float* __restrict__ b2,
    const float* __restrict__ c1, const float* __restrict__ c2,
    float* __restrict__ bs_low, float* __restrict__ cs_low)
{
    __shared__ float wt[192 * 32];    // wt[d*32+c] = wl[(6+c)*192+d]
    __shared__ float w1b[192 * 16];
    __shared__ float w2bt[96 * 16];   // w2bt[j*16+c] = b2[c*96+j]
    __shared__ float w1c[192 * 16];
    __shared__ float w2ct[96 * 16];
    int t = threadIdx.x;
    for (int i = t; i < 32 * 192; i += 256) {
        int r = i / 192, dcol = i % 192;
        wt[dcol * 32 + r] = wl[(6 + r) * 192 + dcol];
    }
    for (int i = t; i < 3072; i += 256) { w1b[i] = b1[i]; w1c[i] = c1[i]; }
    for (int i = t; i < 1536; i += 256) {
        int c = i / 96, j = i % 96;
        w2bt[j * 16 + c] = b2[i]; w2ct[j * 16 + c] = c2[i];
    }
    __syncthreads();

    int pos = blockIdx.x * 256 + t;
    int b = pos >> 14, l = pos & 16383;
    const float* lp = low + (size_t)b * DL + l;

    float Bin[16], Cin[16];
    #pragma unroll
    for (int q = 0; q < 16; ++q) { Bin[q] = 0.f; Cin[q] = 0.f; }
    for (int d = 0; d < 192; ++d) {
        float v = lp[(size_t)d * Ll];
        const float4* w4p = reinterpret_cast<const float4*>(&wt[d * 32]);
        #pragma unroll
        for (int q = 0; q < 4; ++q) {
            float4 f = w4p[q];
            Bin[4 * q + 0] += v * f.x; Bin[4 * q + 1] += v * f.y;
            Bin[4 * q + 2] += v * f.z; Bin[4 * q + 3] += v * f.w;
        }
        #pragma unroll
        for (int q = 0; q < 4; ++q) {
            float4 f = w4p[4 + q];
            Cin[4 * q + 0] += v * f.x; Cin[4 * q + 1] += v * f.y;
            Cin[4 * q + 2] += v * f.z; Cin[4 * q + 3] += v * f.w;
        }
    }

    float Bout[16], Cout[16];
    #pragma unroll
    for (int q = 0; q < 16; ++q) { Bout[q] = 0.f; Cout[q] = 0.f; }
    for (int j = 0; j < 96; ++j) {
        float h1 = 0.f, h2 = 0.f, g1 = 0.f, g2 = 0.f;
        #pragma unroll
        for (int q = 0; q < 4; ++q) {
            float4 a = reinterpret_cast<const float4*>(&w1b[j * 16])[q];
            float4 cvec = reinterpret_cast<const float4*>(&w1b[(j + 96) * 16])[q];
            h1 += a.x * Bin[4 * q] + a.y * Bin[4 * q + 1] + a.z * Bin[4 * q + 2] + a.w * Bin[4 * q + 3];
            h2 += cvec.x * Bin[4 * q] + cvec.y * Bin[4 * q + 1] + cvec.z * Bin[4 * q + 2] + cvec.w * Bin[4 * q + 3];
            float4 ac = reinterpret_cast<const float4*>(&w1c[j * 16])[q];
            float4 cc = reinterpret_cast<const float4*>(&w1c[(j + 96) * 16])[q];
            g1 += ac.x * Cin[4 * q] + ac.y * Cin[4 * q + 1] + ac.z * Cin[4 * q + 2] + ac.w * Cin[4 * q + 3];
            g2 += cc.x * Cin[4 * q] + cc.y * Cin[4 * q + 1] + cc.z * Cin[4 * q + 2] + cc.w * Cin[4 * q + 3];
        }
        float gB = geluf(h1) * h2;
        float gC = geluf(g1) * g2;
        #pragma unroll
        for (int q = 0; q < 4; ++q) {
            float4 f = reinterpret_cast<const float4*>(&w2bt[j * 16])[q];
            Bout[4 * q + 0] += f.x * gB; Bout[4 * q + 1] += f.y * gB;
            Bout[4 * q + 2] += f.z * gB; Bout[4 * q + 3] += f.w * gB;
            float4 fc = reinterpret_cast<const float4*>(&w2ct[j * 16])[q];
            Cout[4 * q + 0] += fc.x * gC; Cout[4 * q + 1] += fc.y * gC;
            Cout[4 * q + 2] += fc.z * gC; Cout[4 * q + 3] += fc.w * gC;
        }
    }
    #pragma unroll
    for (int c = 0; c < 16; ++c) {
        bs_low[(size_t)b * 16 * Ll + (size_t)c * Ll + l] = Bout[c];
        cs_low[(size_t)b * 16 * Ll + (size_t)c * Ll + l] = Cout[c];
    }
}

// ---------------------------------------------------------------------------
// K4b: x_dbl (rows 0..37), writes dts_raw and Bs+Bs_low / Cs+Cs_low.
// ---------------------------------------------------------------------------
__global__ __launch_bounds__(256) void xdbl_k(
    const float* __restrict__ xs, const float* __restrict__ xw,
    const float* __restrict__ bs_low, const float* __restrict__ cs_low,
    float* __restrict__ dts_raw, float* __restrict__ bs_sum, float* __restrict__ cs_sum)
{
    __shared__ float wdt[192 * 6];
    __shared__ float wB[192 * 16];
    __shared__ float wC[192 * 16];
    int t = threadIdx.x;
    for (int i = t; i < 38 * 192; i += 256) {
        int r = i / 192, dcol = i % 192;
        float v = xw[i];
        if (r < 6)       wdt[dcol * 6 + r] = v;
        else if (r < 22) wB[dcol * 16 + (r - 6)] = v;
        else             wC[dcol * 16 + (r - 22)] = v;
    }
    __syncthreads();

    int pos = blockIdx.x * 256 + t;
    int b = pos >> 14, l = pos & 16383;
    const float* xp = xs + (size_t)b * DL + l;

    float da[6], Ba[16], Ca[16];
    #pragma unroll
    for (int q = 0; q < 6; ++q) da[q] = 0.f;
    #pragma unroll
    for (int q = 0; q < 16; ++q) { Ba[q] = 0.f; Ca[q] = 0.f; }

    for (int d = 0; d < 192; ++d) {
        float v = xp[(size_t)d * Ll];
        #pragma unroll
        for (int q = 0; q < 3; ++q) {
            float2 f = reinterpret_cast<const float2*>(&wdt[d * 6])[q];
            da[2 * q] += v * f.x; da[2 * q + 1] += v * f.y;
        }
        #pragma unroll
        for (int q = 0; q < 4; ++q) {
            float4 f = reinterpret_cast<const float4*>(&wB[d * 16])[q];
            Ba[4 * q + 0] += v * f.x; Ba[4 * q + 1] += v * f.y;
            Ba[4 * q + 2] += v * f.z; Ba[4 * q + 3] += v * f.w;
        }
        #pragma unroll
        for (int q = 0; q < 4; ++q) {
            float4 f = reinterpret_cast<const float4*>(&wC[d * 16])[q];
            Ca[4 * q + 0] += v * f.x; Ca[4 * q + 1] += v * f.y;
            Ca[4 * q + 2] += v * f.z; Ca[4 * q + 3] += v * f.w;
        }
    }
    #pragma unroll
    for (int r = 0; r < 6; ++r)
        dts_raw[(size_t)b * 6 * Ll + (size_t)r * Ll + l] = da[r];
    #pragma unroll
    for (int c = 0; c < 16; ++c) {
        size_t o = (size_t)b * 16 * Ll + (size_t)c * Ll + l;
        bs_sum[o] = Ba[c] + bs_low[o];
        cs_sum[o] = Ca[c] + cs_low[o];
    }
}

// ---------------------------------------------------------------------------
// K5: depthwise 1-D conv, k=7, dilation 2, pad 6 (same length).
// TRANS=1 writes (B,L,CH) transposed.
// ---------------------------------------------------------------------------
template <int CH, int TRANS>
__global__ __launch_bounds__(256) void conv1d_k(
    const float* __restrict__ in, const float* __restrict__ w, float* __restrict__ out)
{
    int idx = blockIdx.x * 256 + threadIdx.x;   // over B*CH*L
    int l = idx & 16383;
    int bc = idx >> 14;
    int ch = bc % CH;
    int b = bc / CH;
    const float* ip = in + (size_t)bc * Ll;
    float acc = 0.f;
    #pragma unroll
    for (int k = 0; k < 7; ++k) {
        int li = l + 2 * k - 6;
        if (li >= 0 && li < Ll) acc += w[ch * 7 + k] * ip[li];
    }
    if (TRANS) out[((size_t)b * Ll + l) * CH + ch] = acc;
    else       out[(size_t)bc * Ll + l] = acc;
}

// ---------------------------------------------------------------------------
// K6: dt_proj + softplus -> delta (B,D,L)
// ---------------------------------------------------------------------------
__global__ __launch_bounds__(256) void dtproj_k(
    const float* __restrict__ dts_c, const float* __restrict__ dw,
    const float* __restrict__ db, float* __restrict__ delta)
{
    int l = blockIdx.x * 256 + threadIdx.x;
    int d = blockIdx.y, b = blockIdx.z;
    float acc = db[d];
    const float* ip = dts_c + (size_t)b * 6 * Ll + l;
    #pragma unroll
    for (int r = 0; r < 6; ++r) acc += dw[d * 6 + r] * ip[(size_t)r * Ll];
    delta[(size_t)(b * Dd + d) * Ll + l] = softplusf(acc);
}

// ---------------------------------------------------------------------------
// K7: chunked selective scan.  Task = (b,d,chunk); 16 lanes = 16 states.
// ---------------------------------------------------------------------------
__global__ __launch_bounds__(256) void scan_p1_k(
    const float* __restrict__ delta, const float* __restrict__ xs,
    const float* __restrict__ bs_c, const float* __restrict__ A_logs,
    float* __restrict__ S_buf, float* __restrict__ hend)
{
    int gt = blockIdx.x * 256 + threadIdx.x;
    int n = gt & 15;
    int task = gt >> 4;                // 0..49151
    int chunk = task & (NCHUNK - 1);
    int bd = task >> 7;                // b*192+d
    int d = bd % 192, b = bd / 192;
    float An = -__expf(A_logs[d * 16 + n]);
    const float* dp = delta + (size_t)bd * Ll + chunk * CLEN;
    const float* up = xs + (size_t)bd * Ll + chunk * CLEN;
    const float* bp = bs_c + ((size_t)b * Ll + (size_t)chunk * CLEN) * 16 + n;
    float h = 0.f, S = 0.f;
    for (int tt = 0; tt < CLEN; ++tt) {
        float dlt = dp[tt];
        float u = up[tt];
        float Bn = bp[(size_t)tt * 16];
        S += dlt;
        h = __expf(dlt * An) * h + dlt * u * Bn;
    }
    hend[(size_t)task * 16 + n] = h;
    if (n == 0) S_buf[task] = S;
}

__global__ __launch_bounds__(256) void scan_p2_k(
    const float* __restrict__ S_buf, const float* __restrict__ hend,
    const float* __restrict__ A_logs, float* __restrict__ hin)
{
    int gt = blockIdx.x * 256 + threadIdx.x;
    int n = gt & 15;
    int bd = gt >> 4;
    if (bd >= Bb * Dd) return;
    int d = bd % 192;
    float An = -__expf(A_logs[d * 16 + n]);
    float h = 0.f;
    for (int c = 0; c < NCHUNK; ++c) {
        size_t task = (size_t)bd * NCHUNK + c;
        hin[task * 16 + n] = h;
        h = __expf(An * S_buf[task]) * h + hend[task * 16 + n];
    }
}

__global__ __launch_bounds__(256) void scan_p3_k(
    const float* __restrict__ delta, const float* __restrict__ xs,
    const float* __restrict__ bs_c, const float* __restrict__ cs_c,
    const float* __restrict__ hin, const float* __restrict__ A_logs,
    const float* __restrict__ Ds, float* __restrict__ y)
{
    int gt = blockIdx.x * 256 + threadIdx.x;
    int n = gt & 15;
    int task = gt >> 4;
    int chunk = task & (NCHUNK - 1);
    int bd = task >> 7;
    int d = bd % 192, b = bd / 192;
    float An = -__expf(A_logs[d * 16 + n]);
    float Ddv = Ds[d];
    const float* dp = delta + (size_t)bd * Ll + chunk * CLEN;
    const float* up = xs + (size_t)bd * Ll + chunk * CLEN;
    const float* bp = bs_c + ((size_t)b * Ll + (size_t)chunk * CLEN) * 16 + n;
    const float* cp = cs_c + ((size_t)b * Ll + (size_t)chunk * CLEN) * 16 + n;
    float* yp = y + (size_t)bd * Ll + chunk * CLEN;
    float h = hin[(size_t)task * 16 + n];
    for (int tt = 0; tt < CLEN; ++tt) {
        float dlt = dp[tt];
        float u = up[tt];
        float Bn = bp[(size_t)tt * 16];
        float Cn = cp[(size_t)tt * 16];
        h = __expf(dlt * An) * h + dlt * u * Bn;
        float p = h * Cn;
        p += __shfl_xor(p, 1);
        p += __shfl_xor(p, 2);
        p += __shfl_xor(p, 4);
        p += __shfl_xor(p, 8);
        if (n == 0) yp[tt] = p + Ddv * u;
    }
}

// ---------------------------------------------------------------------------
// K8: out-LayerNorm over D=192 + silu(z) gating.  Tile of 32 positions.
// ---------------------------------------------------------------------------
__global__ __launch_bounds__(256) void outln_k(
    const float* __restrict__ y, const float* __restrict__ z,
    const float* __restrict__ og, const float* __restrict__ ob,
    float* __restrict__ gated)
{
    __shared__ float ly[192 * 32];
    __shared__ float redS[512];
    __shared__ float meanS[32], rstdS[32];
    int t = threadIdx.x;
    int pos0 = blockIdx.x * 32;
    int b = pos0 >> 14, l0 = pos0 & 16383;
    const float* yb = y + (size_t)b * DL + l0;
    #pragma unroll
    for (int i = 0; i < 6; ++i) {
        int f4i = t + i * 256;          // 0..1535
        int dch = f4i >> 3, lq = f4i & 7;
        float4 v = *reinterpret_cast<const float4*>(yb + (size_t)dch * Ll + lq * 4);
        *reinterpret_cast<float4*>(&ly[dch * 32 + lq * 4]) = v;
    }
    __syncthreads();
    int p = t & 31, part = t >> 5;      // 8 parts x 24 channels
    float s = 0.f, s2 = 0.f;
    for (int dch = part * 24; dch < part * 24 + 24; ++dch) {
        float v = ly[dch * 32 + p]; s += v; s2 += v * v;
    }
    redS[part * 32 + p] = s; redS[256 + part * 32 + p] = s2;
    __syncthreads();
    if (t < 32) {
        float ts = 0.f, ts2 = 0.f;
        #pragma unroll
        for (int q = 0; q < 8; ++q) { ts += redS[q * 32 + t]; ts2 += redS[256 + q * 32 + t]; }
        float mean = ts * (1.f / 192.f);
        float var = ts2 * (1.f / 192.f) - mean * mean;
        meanS[t] = mean; rstdS[t] = rsqrtf(var + 1e-5f);
    }
    __syncthreads();
    float mean = meanS[p], rstd = rstdS[p];
    size_t gbase = ((size_t)pos0 + p) * Dd;
    #pragma unroll
    for (int i = 0; i < 6; ++i) {
        int dch = part * 24 + i * 4;
        float4 zv = *reinterpret_cast<const float4*>(z + gbase + dch);
        float4 r;
        r.x = ((ly[(dch + 0) * 32 + p] - mean) * rstd * og[dch + 0] + ob[dch + 0]) * siluf(zv.x);
        r.y = ((ly[(dch + 1) * 32 + p] - mean) * rstd * og[dch + 1] + ob[dch + 1]) * siluf(zv.y);
        r.z = ((ly[(dch + 2) * 32 + p] - mean) * rstd * og[dch + 2] + ob[dch + 2]) * siluf(zv.z);
        r.w = ((ly[(dch + 3) * 32 + p] - mean) * rstd * og[dch + 3] + ob[dch + 3]) * siluf(zv.w);
        *reinterpret_cast<float4*>(gated + gbase + dch) = r;
    }
}

// ---------------------------------------------------------------------------
// K9: out_proj GEMM (M=32768, K=192, N=96) + residual x.
// ---------------------------------------------------------------------------
__global__ __launch_bounds__(256) void outproj_k(
    const float* __restrict__ g, const float* __restrict__ W,
    const float* __restrict__ x, float* __restrict__ out)
{
    __shared__ float la[48 * 68];     // [k][row]
    __shared__ float lw[48 * 97];     // [k][c] padded
    int t = threadIdx.x;
    int m0 = blockIdx.x * 64;
    int tc = t & 15, tr = t >> 4;
    float acc[4][6];
    #pragma unroll
    for (int q = 0; q < 4; ++q)
        #pragma unroll
        for (int j = 0; j < 6; ++j) acc[q][j] = 0.f;

    for (int k0 = 0; k0 < 192; k0 += 48) {
        __syncthreads();
        #pragma unroll
        for (int i = 0; i < 3; ++i) {
            int f4i = t + i * 256;     // 0..767
            int row = f4i / 12, c4 = f4i % 12;
            float4 v = *reinterpret_cast<const float4*>(g + (size_t)(m0 + row) * 192 + k0 + c4 * 4);
            int c = c4 * 4;
            la[(c + 0) * 68 + row] = v.x; la[(c + 1) * 68 + row] = v.y;
            la[(c + 2) * 68 + row] = v.z; la[(c + 3) * 68 + row] = v.w;
        }
        #pragma unroll
        for (int i = 0; i < 18; ++i) {
            int idx = t + i * 256;     // 0..4607
            int c = idx / 48, k = idx % 48;
            lw[k * 97 + c] = W[(size_t)c * 192 + k0 + k];
        }
        __syncthreads();
        for (int k = 0; k < 48; ++k) {
            float4 a4 = *reinterpret_cast<const float4*>(&la[k * 68 + tr * 4]);
            float av0 = a4.x, av1 = a4.y, av2 = a4.z, av3 = a4.w;
            #pragma unroll
            for (int j = 0; j < 6; ++j) {
                float wv = lw[k * 97 + tc * 6 + j];
                acc[0][j] += av0 * wv; acc[1][j] += av1 * wv;
                acc[2][j] += av2 * wv; acc[3][j] += av3 * wv;
            }
        }
    }
    #pragma unroll
    for (int q = 0; q < 4; ++q) {
        int m = m0 + tr * 4 + q;
        #pragma unroll
        for (int j = 0; j < 6; ++j) {
            int c = tc * 6 + j;
            out[(size_t)m * 96 + c] = acc[q][j] + x[(size_t)m * 96 + c];
        }
    }
}

// ---------------------------------------------------------------------------
extern "C" void kernel_launch(void* const* d_in, const int* in_sizes, int n_in,
                              void* d_out, int out_size, void* d_ws, size_t ws_size,
                              hipStream_t stream)
{
    const float* x            = (const float*)d_in[0];
    const float* hbl          = (const float*)d_in[1];
    const float* ln_g         = (const float*)d_in[2];
    const float* ln_b         = (const float*)d_in[3];
    const float* in_proj_w    = (const float*)d_in[4];
    const float* in_proj_low_w= (const float*)d_in[5];
    const float* conv2d_w     = (const float*)d_in[6];
    const float* conv2d_b     = (const float*)d_in[7];
    const float* x_proj_w     = (const float*)d_in[8];
    const float* x_proj_w_low = (const float*)d_in[9];
    const float* conv_dt_w    = (const float*)d_in[10];
    const float* conv_B_w     = (const float*)d_in[11];
    const float* conv_C_w     = (const float*)d_in[12];
    const float* sgb_w1       = (const float*)d_in[13];
    const float* sgb_w2       = (const float*)d_in[14];
    const float* sgc_w1       = (const float*)d_in[15];
    const float* sgc_w2       = (const float*)d_in[16];
    const float* dt_proj_w    = (const float*)d_in[17];
    const float* dt_proj_b    = (const float*)d_in[18];
    const float* A_logs       = (const float*)d_in[19];
    const float* Ds           = (const float*)d_in[20];
    const float* outn_g       = (const float*)d_in[21];
    const float* outn_b       = (const float*)d_in[22];
    const float* out_proj_w   = (const float*)d_in[23];
    float* out = (float*)d_out;
    float* ws  = (float*)d_ws;

    // workspace layout (floats)
    float* z       = ws;                       // 6,291,456
    float* xi_raw  = z + 6291456;              // reused as delta
    float* xs      = xi_raw + 6291456;         // reused as gated
    float* low     = xs + 6291456;             // reused as y
    float* bs_low  = low + 6291456;            // 524,288
    float* cs_low  = bs_low + 524288;
    float* dts_raw = cs_low + 524288;          // 196,608
    float* bs_sum  = dts_raw + 196608;
    float* cs_sum  = bs_sum + 524288;
    float* dts_c   = cs_sum + 524288;
    float* bs_c    = dts_c + 196608;           // (B,L,16)
    float* cs_c    = bs_c + 524288;
    float* S_buf   = cs_c + 524288;            // 49,152
    float* hend    = S_buf + 49152;            // 786,432
    float* hin     = hend + 786432;            // 786,432
    float* delta   = xi_raw;
    float* y       = low;
    float* gated   = xs;

    // 1) LN + in_proj (xi channel-major, z pos-major)
    gemm96_k<0><<<dim3(512, 6), 256, 0, stream>>>(x, in_proj_w, xi_raw, z, ln_g, ln_b);
    // 2) in_proj_low
    gemm96_k<1><<<dim3(512, 3), 256, 0, stream>>>(hbl, in_proj_low_w, low, nullptr, nullptr, nullptr);
    // 3) depthwise 3x3 + SiLU
    conv3x3_k<<<dim3(128, 192, 2), 128, 0, stream>>>(xi_raw, conv2d_w, conv2d_b, xs);
    // 4) low_dbl + SimpleGates
    lowdbl_gates_k<<<128, 256, 0, stream>>>(low, x_proj_w_low, sgb_w1, sgb_w2, sgc_w1, sgc_w2,
                                            bs_low, cs_low);
    // 5) x_dbl + sums
    xdbl_k<<<128, 256, 0, stream>>>(xs, x_proj_w, bs_low, cs_low, dts_raw, bs_sum, cs_sum);
    // 6) 1-D dilated depthwise convs
    conv1d_k<6, 0><<<768, 256, 0, stream>>>(dts_raw, conv_dt_w, dts_c);
    conv1d_k<16, 1><<<2048, 256, 0, stream>>>(bs_sum, conv_B_w, bs_c);
    conv1d_k<16, 1><<<2048, 256, 0, stream>>>(cs_sum, conv_C_w, cs_c);
    // 7) dt_proj + softplus (delta reuses xi_raw)
    dtproj_k<<<dim3(64, 192, 2), 256, 0, stream>>>(dts_c, dt_proj_w, dt_proj_b, delta);
    // 8) chunked selective scan
    scan_p1_k<<<3072, 256, 0, stream>>>(delta, xs, bs_c, A_logs, S_buf, hend);
    scan_p2_k<<<24, 256, 0, stream>>>(S_buf, hend, A_logs, hin);
    scan_p3_k<<<3072, 256, 0, stream>>>(delta, xs, bs_c, cs_c, hin, A_logs, Ds, y);
    // 9) out-LN + silu(z) gate (gated reuses xs)
    outln_k<<<1024, 256, 0, stream>>>(y, z, outn_g, outn_b, gated);
    // 10) out_proj + residual
    outproj_k<<<512, 256, 0, stream>>>(gated, out_proj_w, x, out);
}